// Round 1
// baseline (1214.367 us; speedup 1.0000x reference)
//
#include <hip/hip_runtime.h>
#include <hip/hip_bf16.h>
#include <math.h>

#define D 256
#define FT_STRIDE 72   // shorts; 144 B rows, 16B-aligned; b128 walk reads hit the 8-clk floor

typedef short v8s __attribute__((ext_vector_type(8)));
typedef float f32x4 __attribute__((ext_vector_type(4)));
typedef float f32x16 __attribute__((ext_vector_type(16)));

__device__ __forceinline__ unsigned short f2b(float f) {
    return __bfloat16_as_ushort(__float2bfloat16(f));
}
__device__ __forceinline__ float b2f(unsigned short u) {
    return __bfloat162float(__ushort_as_bfloat16(u));
}

// async global->LDS, 16 B per lane (guide m97 pattern)
__device__ __forceinline__ void gload16(const void* g, void* l) {
    __builtin_amdgcn_global_load_lds(
        (const __attribute__((address_space(1))) void*)g,
        (__attribute__((address_space(3))) void*)l, 16, 0, 0);
}

// ---------------- prep: segstart + wconv(Wf,32x32) + wconv(Wt,16x16) + zero xg
__global__ void prep_kernel(const int* __restrict__ batch, int* __restrict__ seg_start,
                            const float* __restrict__ Wf, unsigned short* __restrict__ Wb32,
                            const float* __restrict__ Wt, unsigned short* __restrict__ Wtb,
                            float* __restrict__ xg, int N, int B) {
    const int blk = blockIdx.x, tid = threadIdx.x;
    if (blk < 40) {
        int b = blk * 256 + tid;
        if (b > B) return;
        int lo = 0, hi = N;
        while (lo < hi) {
            int mid = (lo + hi) >> 1;
            if (batch[mid] < b) lo = mid + 1; else hi = mid;
        }
        seg_start[b] = lo;
    } else if (blk < 296) {
        // W_feat -> 32x32x16 B-frag order: B[k][n]: lane=((k>>3)&1)*32+(n&31), j=k&7
        int idx = (blk - 40) * 256 + tid;         // 65536
        int k = idx >> 8, n = idx & 255;
        int lane = ((k >> 3) & 1) * 32 + (n & 31);
        int j = k & 7, kst = k >> 4, ntile = n >> 5;
        Wb32[(((ntile * 16 + kst) * 64) + lane) * 8 + j] = f2b(Wf[k * 256 + n]);
    } else if (blk < 808) {
        // W_t -> 16x16x32 B-frag order (K=512): lane=((k>>3)&3)*16+(n&15), j=k&7
        int idx = (blk - 296) * 256 + tid;        // 131072
        int k = idx >> 8, n = idx & 255;
        int ntile = n >> 4, kst = k >> 5;
        int lane = ((k >> 3) & 3) * 16 + (n & 15);
        int j = k & 7;
        Wtb[(((ntile * 16 + kst) * 64) + lane) * 8 + j] = f2b(Wt[k * 256 + n]);
    } else {
        int idx = (blk - 808) * 256 + tid;        // 640000 float4 = 10.24 MB
        if (idx < 640000) ((float4*)xg)[idx] = make_float4(0.f, 0.f, 0.f, 0.f);
    }
}

// ---------------- K1 (fallback only): gate = x.Wg + bg --------------------
template<bool CONV>
__global__ __launch_bounds__(256) void gate_conv_kernel(
    const float* __restrict__ x, const float* __restrict__ Wg,
    const float* __restrict__ bg, float* __restrict__ gate,
    unsigned short* __restrict__ xb16, int N) {
    const int lane = threadIdx.x & 63;
    const int wid = blockIdx.x * 4 + (threadIdx.x >> 6);
    const int nw = gridDim.x * 4;
    const float4 wv = *(const float4*)(Wg + lane * 4);
    const float bgv = bg[0];
    for (int n = wid * 2; n < N; n += nw * 2) {
        const float4 xv0 = *(const float4*)(x + (size_t)n * D + lane * 4);
        const float4 xv1 = *(const float4*)(x + (size_t)(n + 1) * D + lane * 4);
        if (CONV) {
            ushort4 h0 = { f2b(xv0.x), f2b(xv0.y), f2b(xv0.z), f2b(xv0.w) };
            ushort4 h1 = { f2b(xv1.x), f2b(xv1.y), f2b(xv1.z), f2b(xv1.w) };
            *(ushort4*)(xb16 + (size_t)n * D + lane * 4) = h0;
            *(ushort4*)(xb16 + (size_t)(n + 1) * D + lane * 4) = h1;
        }
        float d0 = xv0.x * wv.x + xv0.y * wv.y + xv0.z * wv.z + xv0.w * wv.w;
        float d1 = xv1.x * wv.x + xv1.y * wv.y + xv1.z * wv.z + xv1.w * wv.w;
        #pragma unroll
        for (int off = 32; off; off >>= 1) {
            d0 += __shfl_xor(d0, off, 64);
            d1 += __shfl_xor(d1, off, 64);
        }
        if (lane == 0) { gate[n] = d0 + bgv; gate[n + 1] = d1 + bgv; }
    }
}

// ---------------- K1b: per-graph softmax stats (max, 1/sum) ----------------
__global__ __launch_bounds__(256) void stats_kernel(const float* __restrict__ gate,
                                                    const int* __restrict__ seg_start,
                                                    float* __restrict__ mvec,
                                                    float* __restrict__ invs, int B) {
    int wid = blockIdx.x * 4 + (threadIdx.x >> 6);
    int lane = threadIdx.x & 63;
    if (wid >= B) return;
    int s0 = seg_start[wid], s1 = seg_start[wid + 1];
    float m = -INFINITY;
    for (int i = s0 + lane; i < s1; i += 64) m = fmaxf(m, gate[i]);
    #pragma unroll
    for (int off = 32; off > 0; off >>= 1) m = fmaxf(m, __shfl_xor(m, off, 64));
    float s = 0.f;
    for (int i = s0 + lane; i < s1; i += 64) s += __expf(gate[i] - m);
    #pragma unroll
    for (int off = 32; off > 0; off >>= 1) s += __shfl_xor(s, off, 64);
    if (lane == 0) { mvec[wid] = m; invs[wid] = (s > 0.f) ? 1.f / s : 0.f; }
}

// ---------------- NEW pass 1: fused gate + feat GEMM, feat image to global -
// Reads x fp32 ONCE (64 B/lane/k-step -> ~32 KB/CU in flight, BW-bound);
// GEMM (65 GF bf16) and fp32 gate dot ride under the mandatory stream.
// Output: per-block col-major bf16 image [256 cols][FT_STRIDE rows] (36864 B).
__global__ __launch_bounds__(256, 4) void featgate_kernel(
    const float* __restrict__ x, const unsigned short* __restrict__ Wb32,
    const float* __restrict__ Wg, const float* __restrict__ bg,
    const float* __restrict__ bfeat, float* __restrict__ gate,
    unsigned short* __restrict__ featbuf, int N) {

    __shared__ unsigned short feat_s[256 * FT_STRIDE] __attribute__((aligned(16)));

    const int tid = threadIdx.x;
    const int n0 = blockIdx.x * 64;
    const int w = tid >> 6, lane = tid & 63;
    const int l31 = lane & 31, lh = lane >> 5;

    f32x16 acc[2][2];
    #pragma unroll
    for (int i = 0; i < 2; i++)
        #pragma unroll
        for (int j = 0; j < 2; j++)
            #pragma unroll
            for (int e = 0; e < 16; e++) acc[i][j][e] = 0.f;

    unsigned abase[2];               // element index, < 1.28e8, fits u32
    #pragma unroll
    for (int rt = 0; rt < 2; rt++) {
        int r = n0 + rt * 32 + l31;
        if (r > N - 1) r = N - 1;
        abase[rt] = (unsigned)r * D + lh * 8;
    }

    float gd0 = 0.f, gd1 = 0.f;      // fp32 gate partials (wave 0 only)
    v8s A[3][2], Bf[2][2];

    // load fp32 chunk k into A slot s; wave 0 also accumulates the gate dot
    #define LOADA(s, k)                                                      \
    {                                                                        \
        _Pragma("unroll")                                                    \
        for (int rt = 0; rt < 2; rt++) {                                     \
            const float* src = x + abase[rt] + (k) * 16;                     \
            float4 f0 = *(const float4*)src, f1 = *(const float4*)(src + 4); \
            if (w == 0) {                                                    \
                float4 g0 = *(const float4*)(Wg + lh * 8 + (k) * 16);        \
                float4 g1 = *(const float4*)(Wg + lh * 8 + (k) * 16 + 4);    \
                float t = f0.x * g0.x + f0.y * g0.y + f0.z * g0.z            \
                        + f0.w * g0.w + f1.x * g1.x + f1.y * g1.y            \
                        + f1.z * g1.z + f1.w * g1.w;                         \
                if (rt == 0) gd0 += t; else gd1 += t;                        \
            }                                                                \
            v8s v;                                                           \
            v[0] = (short)f2b(f0.x); v[1] = (short)f2b(f0.y);                \
            v[2] = (short)f2b(f0.z); v[3] = (short)f2b(f0.w);                \
            v[4] = (short)f2b(f1.x); v[5] = (short)f2b(f1.y);                \
            v[6] = (short)f2b(f1.z); v[7] = (short)f2b(f1.w);                \
            A[s][rt] = v;                                                    \
        }                                                                    \
    }

    #pragma unroll
    for (int p = 0; p < 2; p++) {
        LOADA(p, p)
        #pragma unroll
        for (int ct = 0; ct < 2; ct++)
            Bf[p][ct] = *(const v8s*)(Wb32 + (((size_t)(w * 2 + ct) * 16 + p) * 64 + lane) * 8);
    }

    #pragma unroll
    for (int ks = 0; ks < 16; ks++) {
        const int cs = ks % 3, bs = ks & 1;
        if (ks < 14) LOADA((ks + 2) % 3, ks + 2)
        if (ks < 15) {
            const int nb = (ks + 1) & 1;
            #pragma unroll
            for (int ct = 0; ct < 2; ct++)
                Bf[nb][ct] = *(const v8s*)(Wb32 + (((size_t)(w * 2 + ct) * 16 + ks + 1) * 64 + lane) * 8);
        }
        #pragma unroll
        for (int rt = 0; rt < 2; rt++)
            #pragma unroll
            for (int ct = 0; ct < 2; ct++)
                acc[rt][ct] = __builtin_amdgcn_mfma_f32_32x32x16_bf16(
                    A[cs][rt], Bf[bs][ct], acc[rt][ct], 0, 0, 0);
    }
    #undef LOADA

    // gate finalize: row r = abase>>8 (lh==0); clamped tail rows write same value
    if (w == 0) {
        const float bgv = bg[0];
        #pragma unroll
        for (int rt = 0; rt < 2; rt++) {
            float d = (rt == 0) ? gd0 : gd1;
            d += __shfl_xor(d, 32, 64);
            if (lh == 0) gate[abase[rt] >> 8] = d + bgv;
        }
    }

    // epilogue: bias + leaky -> bf16 transposed LDS (NO alpha here; pass 3 applies it)
    // C/D 32x32: col=lane&31, row=(reg&3)+8*(reg>>2)+4*(lane>>5)
    #pragma unroll
    for (int ct = 0; ct < 2; ct++) {
        int col = w * 64 + ct * 32 + l31;
        float bias = bfeat[col];
        #pragma unroll
        for (int rt = 0; rt < 2; rt++) {
            #pragma unroll
            for (int g = 0; g < 4; g++) {
                int rbase = rt * 32 + g * 8 + 4 * lh;
                ushort4 h;
                #pragma unroll
                for (int rr = 0; rr < 4; rr++) {
                    float y = acc[rt][ct][g * 4 + rr] + bias;
                    y = (y >= 0.f) ? y : 0.01f * y;
                    ((unsigned short*)&h)[rr] = f2b(y);
                }
                *(ushort4*)(&feat_s[col * FT_STRIDE + rbase]) = h;
            }
        }
    }
    __syncthreads();

    // linear image copy LDS->global, coalesced 16 B/lane (pad rows included)
    unsigned short* dst = featbuf + (size_t)blockIdx.x * (256 * FT_STRIDE);
    #pragma unroll
    for (int it = 0; it < 9; it++) {
        int off = it * 2048 + tid * 8;           // shorts
        *(v8s*)(dst + off) = *(const v8s*)(feat_s + off);
    }
}

// ---------------- NEW pass 3: stage image via global_load_lds + alpha walk -
__global__ __launch_bounds__(256, 4) void wsum_kernel(
    const unsigned short* __restrict__ featbuf, const float* __restrict__ gate,
    const int* __restrict__ batch, const float* __restrict__ mvec,
    const float* __restrict__ invs, float* __restrict__ xg, int N) {

    __shared__ unsigned short feat_s[256 * FT_STRIDE] __attribute__((aligned(16)));
    __shared__ float alpha_s[64];
    __shared__ int batch_s[64];

    const int tid = threadIdx.x;
    const int n0 = blockIdx.x * 64;

    const unsigned short* src = featbuf + (size_t)blockIdx.x * (256 * FT_STRIDE);
    #pragma unroll
    for (int it = 0; it < 9; it++) {
        int off = it * 2048 + tid * 8;           // shorts; 16 B per lane, linear
        gload16(src + off, feat_s + off);
    }

    if (tid < 64) {
        int n = n0 + tid;
        if (n < N) {
            int b = batch[n];
            batch_s[tid] = b;
            alpha_s[tid] = __expf(gate[n] - mvec[b]) * invs[b];
        } else {            // pad with last valid segment, zero weight
            batch_s[tid] = batch[N - 1];
            alpha_s[tid] = 0.f;
        }
    }
    __syncthreads();        // waits vmcnt(0) for global_load_lds + alpha_s/batch_s

    // walk: thread tid owns col tid; alpha applied here (broadcast LDS reads)
    float sum = 0.f;
    int cur = batch_s[0];
    #pragma unroll
    for (int i0 = 0; i0 < 64; i0 += 8) {
        v8s f = *(const v8s*)(&feat_s[tid * FT_STRIDE + i0]);
        int b0 = batch_s[i0], b7 = batch_s[i0 + 7];
        if (b0 == b7) {                 // no boundary in group (common)
            if (b0 != cur) {
                atomicAdd(&xg[(size_t)cur * D + tid], sum);
                sum = 0.f; cur = b0;
            }
            float s0 = alpha_s[i0 + 0] * b2f((unsigned short)f[0])
                     + alpha_s[i0 + 1] * b2f((unsigned short)f[1]);
            float s1 = alpha_s[i0 + 2] * b2f((unsigned short)f[2])
                     + alpha_s[i0 + 3] * b2f((unsigned short)f[3]);
            float s2 = alpha_s[i0 + 4] * b2f((unsigned short)f[4])
                     + alpha_s[i0 + 5] * b2f((unsigned short)f[5]);
            float s3 = alpha_s[i0 + 6] * b2f((unsigned short)f[6])
                     + alpha_s[i0 + 7] * b2f((unsigned short)f[7]);
            sum += (s0 + s1) + (s2 + s3);
        } else {
            #pragma unroll
            for (int j = 0; j < 8; j++) {
                int b = batch_s[i0 + j];
                if (b != cur) {
                    atomicAdd(&xg[(size_t)cur * D + tid], sum);
                    sum = 0.f; cur = b;
                }
                sum = fmaf(alpha_s[i0 + j], b2f((unsigned short)f[j]), sum);
            }
        }
    }
    atomicAdd(&xg[(size_t)cur * D + tid], sum);
}

// ---------------- fallback pass 2 (ws too small): fp32-in feat GEMM + walk -
template<bool BF16IN>
__global__ __launch_bounds__(256, 4) void feat_attn_kernel(
    const float* __restrict__ x, const unsigned short* __restrict__ xb16,
    const unsigned short* __restrict__ Wb32,
    const float* __restrict__ bfeat, const float* __restrict__ gate,
    const int* __restrict__ batch, const float* __restrict__ mvec,
    const float* __restrict__ invs, float* __restrict__ xg, int N) {

    __shared__ unsigned short feat_s[256 * FT_STRIDE] __attribute__((aligned(16)));
    __shared__ float alpha_s[64];
    __shared__ int batch_s[64];

    const int tid = threadIdx.x;
    const int n0 = blockIdx.x * 64;

    if (tid < 64) {
        int n = n0 + tid;
        if (n < N) {
            int b = batch[n];
            batch_s[tid] = b;
            alpha_s[tid] = __expf(gate[n] - mvec[b]) * invs[b];
        } else {
            batch_s[tid] = batch[N - 1];
            alpha_s[tid] = 0.f;
        }
    }

    const int w = tid >> 6, lane = tid & 63;
    const int l31 = lane & 31, lh = lane >> 5;

    f32x16 acc[2][2];
    #pragma unroll
    for (int i = 0; i < 2; i++)
        #pragma unroll
        for (int j = 0; j < 2; j++)
            #pragma unroll
            for (int e = 0; e < 16; e++) acc[i][j][e] = 0.f;

    size_t abase[2];
    #pragma unroll
    for (int rt = 0; rt < 2; rt++) {
        int r = n0 + rt * 32 + l31;
        if (r > N - 1) r = N - 1;
        abase[rt] = (size_t)r * D + lh * 8;
    }

    v8s A[3][2], Bf[2][2];
    #pragma unroll
    for (int p = 0; p < 2; p++) {
        #pragma unroll
        for (int rt = 0; rt < 2; rt++) {
            if (BF16IN) A[p][rt] = *(const v8s*)(xb16 + abase[rt] + p * 16);
            else {
                const float* src = x + abase[rt] + p * 16;
                float4 f0 = *(const float4*)src, f1 = *(const float4*)(src + 4);
                v8s v; v[0]=(short)f2b(f0.x); v[1]=(short)f2b(f0.y);
                v[2]=(short)f2b(f0.z); v[3]=(short)f2b(f0.w);
                v[4]=(short)f2b(f1.x); v[5]=(short)f2b(f1.y);
                v[6]=(short)f2b(f1.z); v[7]=(short)f2b(f1.w);
                A[p][rt] = v;
            }
        }
        #pragma unroll
        for (int ct = 0; ct < 2; ct++)
            Bf[p][ct] = *(const v8s*)(Wb32 + (((size_t)(w * 2 + ct) * 16 + p) * 64 + lane) * 8);
    }

    #pragma unroll
    for (int ks = 0; ks < 16; ks++) {
        const int cs = ks % 3, bs = ks & 1;
        if (ks < 14) {
            const int ns = (ks + 2) % 3;
            #pragma unroll
            for (int rt = 0; rt < 2; rt++) {
                if (BF16IN) A[ns][rt] = *(const v8s*)(xb16 + abase[rt] + (ks + 2) * 16);
                else {
                    const float* src = x + abase[rt] + (ks + 2) * 16;
                    float4 f0 = *(const float4*)src, f1 = *(const float4*)(src + 4);
                    v8s v; v[0]=(short)f2b(f0.x); v[1]=(short)f2b(f0.y);
                    v[2]=(short)f2b(f0.z); v[3]=(short)f2b(f0.w);
                    v[4]=(short)f2b(f1.x); v[5]=(short)f2b(f1.y);
                    v[6]=(short)f2b(f1.z); v[7]=(short)f2b(f1.w);
                    A[ns][rt] = v;
                }
            }
        }
        if (ks < 15) {
            const int nb = (ks + 1) & 1;
            #pragma unroll
            for (int ct = 0; ct < 2; ct++)
                Bf[nb][ct] = *(const v8s*)(Wb32 + (((size_t)(w * 2 + ct) * 16 + ks + 1) * 64 + lane) * 8);
        }
        #pragma unroll
        for (int rt = 0; rt < 2; rt++)
            #pragma unroll
            for (int ct = 0; ct < 2; ct++)
                acc[rt][ct] = __builtin_amdgcn_mfma_f32_32x32x16_bf16(
                    A[cs][rt], Bf[bs][ct], acc[rt][ct], 0, 0, 0);
    }

    __syncthreads();

    #pragma unroll
    for (int ct = 0; ct < 2; ct++) {
        int col = w * 64 + ct * 32 + l31;
        float bias = bfeat[col];
        #pragma unroll
        for (int rt = 0; rt < 2; rt++) {
            #pragma unroll
            for (int g = 0; g < 4; g++) {
                int rbase = rt * 32 + g * 8 + 4 * lh;
                ushort4 h;
                #pragma unroll
                for (int rr = 0; rr < 4; rr++) {
                    float y = acc[rt][ct][g * 4 + rr] + bias;
                    y = (y >= 0.f) ? y : 0.01f * y;
                    y *= alpha_s[rbase + rr];
                    ((unsigned short*)&h)[rr] = f2b(y);
                }
                *(ushort4*)(&feat_s[col * FT_STRIDE + rbase]) = h;
            }
        }
    }
    __syncthreads();

    float sum = 0.f;
    int cur = batch_s[0];
    #pragma unroll
    for (int i0 = 0; i0 < 64; i0 += 8) {
        v8s f = *(const v8s*)(&feat_s[tid * FT_STRIDE + i0]);
        int b0 = batch_s[i0], b7 = batch_s[i0 + 7];
        if (b0 == b7) {
            if (b0 != cur) {
                atomicAdd(&xg[(size_t)cur * D + tid], sum);
                sum = 0.f; cur = b0;
            }
            float p0 = b2f((unsigned short)f[0]) + b2f((unsigned short)f[1]);
            float p1 = b2f((unsigned short)f[2]) + b2f((unsigned short)f[3]);
            float p2 = b2f((unsigned short)f[4]) + b2f((unsigned short)f[5]);
            float p3 = b2f((unsigned short)f[6]) + b2f((unsigned short)f[7]);
            sum += (p0 + p1) + (p2 + p3);
        } else {
            #pragma unroll
            for (int j = 0; j < 8; j++) {
                int b = batch_s[i0 + j];
                if (b != cur) {
                    atomicAdd(&xg[(size_t)cur * D + tid], sum);
                    sum = 0.f; cur = b;
                }
                sum += b2f((unsigned short)f[j]);
            }
        }
    }
    atomicAdd(&xg[(size_t)cur * D + tid], sum);
}

// ---------------- K3 (MFMA, fused cat conversion) --------------------------
__global__ __launch_bounds__(256) void out_mfma_kernel(
    const float* __restrict__ xg, const float* __restrict__ xg_old,
    const unsigned short* __restrict__ Wtb, const float* __restrict__ bt,
    float* __restrict__ out, int B) {
    const int tid = threadIdx.x;
    const int w = tid >> 6, lane = tid & 63, mrow = lane & 15, q = lane >> 4;
    const int r0 = blockIdx.x * 64;

    f32x4 acc[4][4];
    #pragma unroll
    for (int i = 0; i < 4; i++)
        #pragma unroll
        for (int j = 0; j < 4; j++) acc[i][j] = (f32x4){0.f, 0.f, 0.f, 0.f};

    size_t rowbase[4];
    #pragma unroll
    for (int rb = 0; rb < 4; rb++) {
        int r = r0 + rb * 16 + mrow;
        if (r > B - 1) r = B - 1;
        rowbase[rb] = (size_t)r * D + q * 8;
    }

    #pragma unroll
    for (int ks = 0; ks < 16; ks++) {
        v8s a[4], bfr[4];
        #pragma unroll
        for (int rb = 0; rb < 4; rb++) {
            const float* src = (ks < 8) ? (xg + rowbase[rb] + ks * 32)
                                        : (xg_old + rowbase[rb] + (ks - 8) * 32);
            float4 f0 = *(const float4*)src;
            float4 f1 = *(const float4*)(src + 4);
            v8s v;
            v[0] = (short)f2b(f0.x); v[1] = (short)f2b(f0.y);
            v[2] = (short)f2b(f0.z); v[3] = (short)f2b(f0.w);
            v[4] = (short)f2b(f1.x); v[5] = (short)f2b(f1.y);
            v[6] = (short)f2b(f1.z); v[7] = (short)f2b(f1.w);
            a[rb] = v;
        }
        #pragma unroll
        for (int cb = 0; cb < 4; cb++)
            bfr[cb] = *(const v8s*)(Wtb + (((size_t)(w * 4 + cb) * 16 + ks) * 64 + lane) * 8);
        #pragma unroll
        for (int rb = 0; rb < 4; rb++)
            #pragma unroll
            for (int cb = 0; cb < 4; cb++)
                acc[rb][cb] = __builtin_amdgcn_mfma_f32_16x16x32_bf16(
                    a[rb], bfr[cb], acc[rb][cb], 0, 0, 0);
    }

    #pragma unroll
    for (int cb = 0; cb < 4; cb++) {
        int col = w * 64 + cb * 16 + mrow;
        float bias = bt[col];
        #pragma unroll
        for (int rb = 0; rb < 4; rb++) {
            #pragma unroll
            for (int reg = 0; reg < 4; reg++) {
                int row = r0 + rb * 16 + q * 4 + reg;
                if (row < B) {
                    float y = acc[rb][cb][reg] + bias;
                    y = (y >= 0.f) ? y : 0.01f * y;
                    out[(size_t)row * D + col] = y + xg_old[(size_t)row * D + col];
                }
            }
        }
    }
}

// ---------------------------------------------------------------------------
extern "C" void kernel_launch(void* const* d_in, const int* in_sizes, int n_in,
                              void* d_out, int out_size, void* d_ws, size_t ws_size,
                              hipStream_t stream) {
    const float* xg_old = (const float*)d_in[0];   // [B, D]
    const float* x      = (const float*)d_in[1];   // [N, D]
    const int*   batch  = (const int*)d_in[2];     // [N], sorted
    const float* W_gate = (const float*)d_in[3];   // [D]
    const float* b_gate = (const float*)d_in[4];   // [1]
    const float* W_feat = (const float*)d_in[5];   // [D, D]
    const float* b_feat = (const float*)d_in[6];   // [D]
    const float* W_t    = (const float*)d_in[7];   // [2D, D]
    const float* b_t    = (const float*)d_in[8];   // [D]
    float* out = (float*)d_out;                    // [B, D]

    const int N = in_sizes[1] / D;                 // 500000
    const int B = in_sizes[0] / D;                 // 10000
    const int nblk = (N + 63) / 64;                // 7813

    // workspace layout
    char* ws = (char*)d_ws;
    int*            seg_start = (int*)ws;                         // 40 KB
    float*          gate      = (float*)(ws + 0x10000);           // 2 MB
    float*          mvec      = (float*)(ws + 0x220000);          // 40 KB
    float*          invs      = (float*)(ws + 0x230000);          // 40 KB
    unsigned short* Wb32      = (unsigned short*)(ws + 0x240000); // 128 KB
    unsigned short* Wtb       = (unsigned short*)(ws + 0x260000); // 256 KB
    float*          xg        = (float*)(ws + 0x2A0000);          // 10.24 MB
    unsigned short* featbuf   = (unsigned short*)(ws + 0xCA0000); // ~275 MB

    const size_t need_full = 0xCA0000 + (size_t)nblk * (256 * FT_STRIDE * 2);
    const bool full = ws_size >= need_full;

    prep_kernel<<<3308, 256, 0, stream>>>(batch, seg_start, W_feat, Wb32, W_t, Wtb, xg, N, B);

    if (full) {
        featgate_kernel<<<nblk, 256, 0, stream>>>(
            x, Wb32, W_gate, b_gate, b_feat, gate, featbuf, N);
        stats_kernel<<<(B + 3) / 4, 256, 0, stream>>>(gate, seg_start, mvec, invs, B);
        wsum_kernel<<<nblk, 256, 0, stream>>>(featbuf, gate, batch, mvec, invs, xg, N);
    } else {
        gate_conv_kernel<false><<<2048, 256, 0, stream>>>(x, W_gate, b_gate, gate, nullptr, N);
        stats_kernel<<<(B + 3) / 4, 256, 0, stream>>>(gate, seg_start, mvec, invs, B);
        feat_attn_kernel<false><<<nblk, 256, 0, stream>>>(
            x, nullptr, Wb32, b_feat, gate, batch, mvec, invs, xg, N);
    }

    out_mfma_kernel<<<(B + 63) / 64, 256, 0, stream>>>(xg, xg_old, Wtb, b_t, out, B);
}

// Round 2
// 1028.174 us; speedup vs baseline: 1.1811x; 1.1811x over previous
//
#include <hip/hip_runtime.h>
#include <hip/hip_bf16.h>
#include <math.h>

#define D 256
#define FT_STRIDE 72   // shorts; 144 B rows, 16B-aligned; b128 walk reads hit the 8-clk floor

typedef short v8s __attribute__((ext_vector_type(8)));
typedef float f32x4 __attribute__((ext_vector_type(4)));
typedef float f32x16 __attribute__((ext_vector_type(16)));

__device__ __forceinline__ unsigned short f2b(float f) {
    return __bfloat16_as_ushort(__float2bfloat16(f));
}
__device__ __forceinline__ float b2f(unsigned short u) {
    return __bfloat162float(__ushort_as_bfloat16(u));
}

// async global->LDS, 16 B per lane (guide m97 pattern)
__device__ __forceinline__ void gload16(const void* g, void* l) {
    __builtin_amdgcn_global_load_lds(
        (const __attribute__((address_space(1))) void*)g,
        (__attribute__((address_space(3))) void*)l, 16, 0, 0);
}

// ---------------- prep: segstart + wconv(Wf,32x32) + wconv(Wt,16x16) + zero xg
__global__ void prep_kernel(const int* __restrict__ batch, int* __restrict__ seg_start,
                            const float* __restrict__ Wf, unsigned short* __restrict__ Wb32,
                            const float* __restrict__ Wt, unsigned short* __restrict__ Wtb,
                            float* __restrict__ xg, int N, int B) {
    const int blk = blockIdx.x, tid = threadIdx.x;
    if (blk < 40) {
        int b = blk * 256 + tid;
        if (b > B) return;
        int lo = 0, hi = N;
        while (lo < hi) {
            int mid = (lo + hi) >> 1;
            if (batch[mid] < b) lo = mid + 1; else hi = mid;
        }
        seg_start[b] = lo;
    } else if (blk < 296) {
        // W_feat -> 32x32x16 B-frag order: B[k][n]: lane=((k>>3)&1)*32+(n&31), j=k&7
        int idx = (blk - 40) * 256 + tid;         // 65536
        int k = idx >> 8, n = idx & 255;
        int lane = ((k >> 3) & 1) * 32 + (n & 31);
        int j = k & 7, kst = k >> 4, ntile = n >> 5;
        Wb32[(((ntile * 16 + kst) * 64) + lane) * 8 + j] = f2b(Wf[k * 256 + n]);
    } else if (blk < 808) {
        // W_t -> 16x16x32 B-frag order (K=512): lane=((k>>3)&3)*16+(n&15), j=k&7
        int idx = (blk - 296) * 256 + tid;        // 131072
        int k = idx >> 8, n = idx & 255;
        int ntile = n >> 4, kst = k >> 5;
        int lane = ((k >> 3) & 3) * 16 + (n & 15);
        int j = k & 7;
        Wtb[(((ntile * 16 + kst) * 64) + lane) * 8 + j] = f2b(Wt[k * 256 + n]);
    } else {
        int idx = (blk - 808) * 256 + tid;        // 640000 float4 = 10.24 MB
        if (idx < 640000) ((float4*)xg)[idx] = make_float4(0.f, 0.f, 0.f, 0.f);
    }
}

// ---------------- K1 (fallback only): gate = x.Wg + bg --------------------
template<bool CONV>
__global__ __launch_bounds__(256) void gate_conv_kernel(
    const float* __restrict__ x, const float* __restrict__ Wg,
    const float* __restrict__ bg, float* __restrict__ gate,
    unsigned short* __restrict__ xb16, int N) {
    const int lane = threadIdx.x & 63;
    const int wid = blockIdx.x * 4 + (threadIdx.x >> 6);
    const int nw = gridDim.x * 4;
    const float4 wv = *(const float4*)(Wg + lane * 4);
    const float bgv = bg[0];
    for (int n = wid * 2; n < N; n += nw * 2) {
        const float4 xv0 = *(const float4*)(x + (size_t)n * D + lane * 4);
        const float4 xv1 = *(const float4*)(x + (size_t)(n + 1) * D + lane * 4);
        if (CONV) {
            ushort4 h0 = { f2b(xv0.x), f2b(xv0.y), f2b(xv0.z), f2b(xv0.w) };
            ushort4 h1 = { f2b(xv1.x), f2b(xv1.y), f2b(xv1.z), f2b(xv1.w) };
            *(ushort4*)(xb16 + (size_t)n * D + lane * 4) = h0;
            *(ushort4*)(xb16 + (size_t)(n + 1) * D + lane * 4) = h1;
        }
        float d0 = xv0.x * wv.x + xv0.y * wv.y + xv0.z * wv.z + xv0.w * wv.w;
        float d1 = xv1.x * wv.x + xv1.y * wv.y + xv1.z * wv.z + xv1.w * wv.w;
        #pragma unroll
        for (int off = 32; off; off >>= 1) {
            d0 += __shfl_xor(d0, off, 64);
            d1 += __shfl_xor(d1, off, 64);
        }
        if (lane == 0) { gate[n] = d0 + bgv; gate[n + 1] = d1 + bgv; }
    }
}

// ---------------- K1b: per-graph softmax stats (max, 1/sum) ----------------
__global__ __launch_bounds__(256) void stats_kernel(const float* __restrict__ gate,
                                                    const int* __restrict__ seg_start,
                                                    float* __restrict__ mvec,
                                                    float* __restrict__ invs, int B) {
    int wid = blockIdx.x * 4 + (threadIdx.x >> 6);
    int lane = threadIdx.x & 63;
    if (wid >= B) return;
    int s0 = seg_start[wid], s1 = seg_start[wid + 1];
    float m = -INFINITY;
    for (int i = s0 + lane; i < s1; i += 64) m = fmaxf(m, gate[i]);
    #pragma unroll
    for (int off = 32; off > 0; off >>= 1) m = fmaxf(m, __shfl_xor(m, off, 64));
    float s = 0.f;
    for (int i = s0 + lane; i < s1; i += 64) s += __expf(gate[i] - m);
    #pragma unroll
    for (int off = 32; off > 0; off >>= 1) s += __shfl_xor(s, off, 64);
    if (lane == 0) { mvec[wid] = m; invs[wid] = (s > 0.f) ? 1.f / s : 0.f; }
}

// ---------------- pass 1: fused gate + feat GEMM, feat image to global -----
// Reads x fp32 ONCE; GEMM (65 GF bf16) + fp32 gate dot ride under the stream.
// __launch_bounds__(256, 2): 256-reg/wave budget. acc = 64 AGPR; fp32 LOADA
// needs ~70 arch VGPRs live (A 24 + Bf 16 + 4 in-flight float4 + Wg + addr).
// (256,4) capped the unified file at 128 -> 56 regs spilled to scratch
// (WRITE_SIZE showed +450 MB = 226 B/thread) and serialized the prefetch.
__global__ __launch_bounds__(256, 2) void featgate_kernel(
    const float* __restrict__ x, const unsigned short* __restrict__ Wb32,
    const float* __restrict__ Wg, const float* __restrict__ bg,
    const float* __restrict__ bfeat, float* __restrict__ gate,
    unsigned short* __restrict__ featbuf, int N) {

    __shared__ unsigned short feat_s[256 * FT_STRIDE] __attribute__((aligned(16)));

    const int tid = threadIdx.x;
    const int n0 = blockIdx.x * 64;
    const int w = tid >> 6, lane = tid & 63;
    const int l31 = lane & 31, lh = lane >> 5;

    f32x16 acc[2][2];
    #pragma unroll
    for (int i = 0; i < 2; i++)
        #pragma unroll
        for (int j = 0; j < 2; j++)
            #pragma unroll
            for (int e = 0; e < 16; e++) acc[i][j][e] = 0.f;

    unsigned abase[2];               // element index, < 1.28e8, fits u32
    #pragma unroll
    for (int rt = 0; rt < 2; rt++) {
        int r = n0 + rt * 32 + l31;
        if (r > N - 1) r = N - 1;
        abase[rt] = (unsigned)r * D + lh * 8;
    }

    float gd0 = 0.f, gd1 = 0.f;      // fp32 gate partials (wave 0 only)
    v8s A[3][2], Bf[2][2];

    // load fp32 chunk k into A slot s; wave 0 also accumulates the gate dot
    #define LOADA(s, k)                                                      \
    {                                                                        \
        _Pragma("unroll")                                                    \
        for (int rt = 0; rt < 2; rt++) {                                     \
            const float* src = x + abase[rt] + (k) * 16;                     \
            float4 f0 = *(const float4*)src, f1 = *(const float4*)(src + 4); \
            if (w == 0) {                                                    \
                float4 g0 = *(const float4*)(Wg + lh * 8 + (k) * 16);        \
                float4 g1 = *(const float4*)(Wg + lh * 8 + (k) * 16 + 4);    \
                float t = f0.x * g0.x + f0.y * g0.y + f0.z * g0.z            \
                        + f0.w * g0.w + f1.x * g1.x + f1.y * g1.y            \
                        + f1.z * g1.z + f1.w * g1.w;                         \
                if (rt == 0) gd0 += t; else gd1 += t;                        \
            }                                                                \
            v8s v;                                                           \
            v[0] = (short)f2b(f0.x); v[1] = (short)f2b(f0.y);                \
            v[2] = (short)f2b(f0.z); v[3] = (short)f2b(f0.w);                \
            v[4] = (short)f2b(f1.x); v[5] = (short)f2b(f1.y);                \
            v[6] = (short)f2b(f1.z); v[7] = (short)f2b(f1.w);                \
            A[s][rt] = v;                                                    \
        }                                                                    \
    }

    #pragma unroll
    for (int p = 0; p < 2; p++) {
        LOADA(p, p)
        #pragma unroll
        for (int ct = 0; ct < 2; ct++)
            Bf[p][ct] = *(const v8s*)(Wb32 + (((size_t)(w * 2 + ct) * 16 + p) * 64 + lane) * 8);
    }

    #pragma unroll
    for (int ks = 0; ks < 16; ks++) {
        const int cs = ks % 3, bs = ks & 1;
        if (ks < 14) LOADA((ks + 2) % 3, ks + 2)
        if (ks < 15) {
            const int nb = (ks + 1) & 1;
            #pragma unroll
            for (int ct = 0; ct < 2; ct++)
                Bf[nb][ct] = *(const v8s*)(Wb32 + (((size_t)(w * 2 + ct) * 16 + ks + 1) * 64 + lane) * 8);
        }
        #pragma unroll
        for (int rt = 0; rt < 2; rt++)
            #pragma unroll
            for (int ct = 0; ct < 2; ct++)
                acc[rt][ct] = __builtin_amdgcn_mfma_f32_32x32x16_bf16(
                    A[cs][rt], Bf[bs][ct], acc[rt][ct], 0, 0, 0);
    }
    #undef LOADA

    // gate finalize: row r = abase>>8 (lh==0); clamped tail rows write same value
    if (w == 0) {
        const float bgv = bg[0];
        #pragma unroll
        for (int rt = 0; rt < 2; rt++) {
            float d = (rt == 0) ? gd0 : gd1;
            d += __shfl_xor(d, 32, 64);
            if (lh == 0) gate[abase[rt] >> 8] = d + bgv;
        }
    }

    // epilogue: bias + leaky -> bf16 transposed LDS (NO alpha here; pass 3 applies it)
    // C/D 32x32: col=lane&31, row=(reg&3)+8*(reg>>2)+4*(lane>>5)
    #pragma unroll
    for (int ct = 0; ct < 2; ct++) {
        int col = w * 64 + ct * 32 + l31;
        float bias = bfeat[col];
        #pragma unroll
        for (int rt = 0; rt < 2; rt++) {
            #pragma unroll
            for (int g = 0; g < 4; g++) {
                int rbase = rt * 32 + g * 8 + 4 * lh;
                ushort4 h;
                #pragma unroll
                for (int rr = 0; rr < 4; rr++) {
                    float y = acc[rt][ct][g * 4 + rr] + bias;
                    y = (y >= 0.f) ? y : 0.01f * y;
                    ((unsigned short*)&h)[rr] = f2b(y);
                }
                *(ushort4*)(&feat_s[col * FT_STRIDE + rbase]) = h;
            }
        }
    }
    __syncthreads();

    // linear image copy LDS->global, coalesced 16 B/lane (pad rows included)
    unsigned short* dst = featbuf + (size_t)blockIdx.x * (256 * FT_STRIDE);
    #pragma unroll
    for (int it = 0; it < 9; it++) {
        int off = it * 2048 + tid * 8;           // shorts
        *(v8s*)(dst + off) = *(const v8s*)(feat_s + off);
    }
}

// ---------------- pass 3: stage image via global_load_lds + alpha walk -----
__global__ __launch_bounds__(256, 4) void wsum_kernel(
    const unsigned short* __restrict__ featbuf, const float* __restrict__ gate,
    const int* __restrict__ batch, const float* __restrict__ mvec,
    const float* __restrict__ invs, float* __restrict__ xg, int N) {

    __shared__ unsigned short feat_s[256 * FT_STRIDE] __attribute__((aligned(16)));
    __shared__ float alpha_s[64];
    __shared__ int batch_s[64];

    const int tid = threadIdx.x;
    const int n0 = blockIdx.x * 64;

    const unsigned short* src = featbuf + (size_t)blockIdx.x * (256 * FT_STRIDE);
    #pragma unroll
    for (int it = 0; it < 9; it++) {
        int off = it * 2048 + tid * 8;           // shorts; 16 B per lane, linear
        gload16(src + off, feat_s + off);
    }

    if (tid < 64) {
        int n = n0 + tid;
        if (n < N) {
            int b = batch[n];
            batch_s[tid] = b;
            alpha_s[tid] = __expf(gate[n] - mvec[b]) * invs[b];
        } else {            // pad with last valid segment, zero weight
            batch_s[tid] = batch[N - 1];
            alpha_s[tid] = 0.f;
        }
    }
    __syncthreads();        // waits vmcnt(0) for global_load_lds + alpha_s/batch_s

    // walk: thread tid owns col tid; alpha applied here (broadcast LDS reads)
    float sum = 0.f;
    int cur = batch_s[0];
    #pragma unroll
    for (int i0 = 0; i0 < 64; i0 += 8) {
        v8s f = *(const v8s*)(&feat_s[tid * FT_STRIDE + i0]);
        int b0 = batch_s[i0], b7 = batch_s[i0 + 7];
        if (b0 == b7) {                 // no boundary in group (common)
            if (b0 != cur) {
                atomicAdd(&xg[(size_t)cur * D + tid], sum);
                sum = 0.f; cur = b0;
            }
            float s0 = alpha_s[i0 + 0] * b2f((unsigned short)f[0])
                     + alpha_s[i0 + 1] * b2f((unsigned short)f[1]);
            float s1 = alpha_s[i0 + 2] * b2f((unsigned short)f[2])
                     + alpha_s[i0 + 3] * b2f((unsigned short)f[3]);
            float s2 = alpha_s[i0 + 4] * b2f((unsigned short)f[4])
                     + alpha_s[i0 + 5] * b2f((unsigned short)f[5]);
            float s3 = alpha_s[i0 + 6] * b2f((unsigned short)f[6])
                     + alpha_s[i0 + 7] * b2f((unsigned short)f[7]);
            sum += (s0 + s1) + (s2 + s3);
        } else {
            #pragma unroll
            for (int j = 0; j < 8; j++) {
                int b = batch_s[i0 + j];
                if (b != cur) {
                    atomicAdd(&xg[(size_t)cur * D + tid], sum);
                    sum = 0.f; cur = b;
                }
                sum = fmaf(alpha_s[i0 + j], b2f((unsigned short)f[j]), sum);
            }
        }
    }
    atomicAdd(&xg[(size_t)cur * D + tid], sum);
}

// ---------------- fallback pass 2 (ws too small): fp32-in feat GEMM + walk -
template<bool BF16IN>
__global__ __launch_bounds__(256, 4) void feat_attn_kernel(
    const float* __restrict__ x, const unsigned short* __restrict__ xb16,
    const unsigned short* __restrict__ Wb32,
    const float* __restrict__ bfeat, const float* __restrict__ gate,
    const int* __restrict__ batch, const float* __restrict__ mvec,
    const float* __restrict__ invs, float* __restrict__ xg, int N) {

    __shared__ unsigned short feat_s[256 * FT_STRIDE] __attribute__((aligned(16)));
    __shared__ float alpha_s[64];
    __shared__ int batch_s[64];

    const int tid = threadIdx.x;
    const int n0 = blockIdx.x * 64;

    if (tid < 64) {
        int n = n0 + tid;
        if (n < N) {
            int b = batch[n];
            batch_s[tid] = b;
            alpha_s[tid] = __expf(gate[n] - mvec[b]) * invs[b];
        } else {
            batch_s[tid] = batch[N - 1];
            alpha_s[tid] = 0.f;
        }
    }

    const int w = tid >> 6, lane = tid & 63;
    const int l31 = lane & 31, lh = lane >> 5;

    f32x16 acc[2][2];
    #pragma unroll
    for (int i = 0; i < 2; i++)
        #pragma unroll
        for (int j = 0; j < 2; j++)
            #pragma unroll
            for (int e = 0; e < 16; e++) acc[i][j][e] = 0.f;

    size_t abase[2];
    #pragma unroll
    for (int rt = 0; rt < 2; rt++) {
        int r = n0 + rt * 32 + l31;
        if (r > N - 1) r = N - 1;
        abase[rt] = (size_t)r * D + lh * 8;
    }

    v8s A[3][2], Bf[2][2];
    #pragma unroll
    for (int p = 0; p < 2; p++) {
        #pragma unroll
        for (int rt = 0; rt < 2; rt++) {
            if (BF16IN) A[p][rt] = *(const v8s*)(xb16 + abase[rt] + p * 16);
            else {
                const float* src = x + abase[rt] + p * 16;
                float4 f0 = *(const float4*)src, f1 = *(const float4*)(src + 4);
                v8s v; v[0]=(short)f2b(f0.x); v[1]=(short)f2b(f0.y);
                v[2]=(short)f2b(f0.z); v[3]=(short)f2b(f0.w);
                v[4]=(short)f2b(f1.x); v[5]=(short)f2b(f1.y);
                v[6]=(short)f2b(f1.z); v[7]=(short)f2b(f1.w);
                A[p][rt] = v;
            }
        }
        #pragma unroll
        for (int ct = 0; ct < 2; ct++)
            Bf[p][ct] = *(const v8s*)(Wb32 + (((size_t)(w * 2 + ct) * 16 + p) * 64 + lane) * 8);
    }

    #pragma unroll
    for (int ks = 0; ks < 16; ks++) {
        const int cs = ks % 3, bs = ks & 1;
        if (ks < 14) {
            const int ns = (ks + 2) % 3;
            #pragma unroll
            for (int rt = 0; rt < 2; rt++) {
                if (BF16IN) A[ns][rt] = *(const v8s*)(xb16 + abase[rt] + (ks + 2) * 16);
                else {
                    const float* src = x + abase[rt] + (ks + 2) * 16;
                    float4 f0 = *(const float4*)src, f1 = *(const float4*)(src + 4);
                    v8s v; v[0]=(short)f2b(f0.x); v[1]=(short)f2b(f0.y);
                    v[2]=(short)f2b(f0.z); v[3]=(short)f2b(f0.w);
                    v[4]=(short)f2b(f1.x); v[5]=(short)f2b(f1.y);
                    v[6]=(short)f2b(f1.z); v[7]=(short)f2b(f1.w);
                    A[ns][rt] = v;
                }
            }
        }
        if (ks < 15) {
            const int nb = (ks + 1) & 1;
            #pragma unroll
            for (int ct = 0; ct < 2; ct++)
                Bf[nb][ct] = *(const v8s*)(Wb32 + (((size_t)(w * 2 + ct) * 16 + ks + 1) * 64 + lane) * 8);
        }
        #pragma unroll
        for (int rt = 0; rt < 2; rt++)
            #pragma unroll
            for (int ct = 0; ct < 2; ct++)
                acc[rt][ct] = __builtin_amdgcn_mfma_f32_32x32x16_bf16(
                    A[cs][rt], Bf[bs][ct], acc[rt][ct], 0, 0, 0);
    }

    __syncthreads();

    #pragma unroll
    for (int ct = 0; ct < 2; ct++) {
        int col = w * 64 + ct * 32 + l31;
        float bias = bfeat[col];
        #pragma unroll
        for (int rt = 0; rt < 2; rt++) {
            #pragma unroll
            for (int g = 0; g < 4; g++) {
                int rbase = rt * 32 + g * 8 + 4 * lh;
                ushort4 h;
                #pragma unroll
                for (int rr = 0; rr < 4; rr++) {
                    float y = acc[rt][ct][g * 4 + rr] + bias;
                    y = (y >= 0.f) ? y : 0.01f * y;
                    y *= alpha_s[rbase + rr];
                    ((unsigned short*)&h)[rr] = f2b(y);
                }
                *(ushort4*)(&feat_s[col * FT_STRIDE + rbase]) = h;
            }
        }
    }
    __syncthreads();

    float sum = 0.f;
    int cur = batch_s[0];
    #pragma unroll
    for (int i0 = 0; i0 < 64; i0 += 8) {
        v8s f = *(const v8s*)(&feat_s[tid * FT_STRIDE + i0]);
        int b0 = batch_s[i0], b7 = batch_s[i0 + 7];
        if (b0 == b7) {
            if (b0 != cur) {
                atomicAdd(&xg[(size_t)cur * D + tid], sum);
                sum = 0.f; cur = b0;
            }
            float p0 = b2f((unsigned short)f[0]) + b2f((unsigned short)f[1]);
            float p1 = b2f((unsigned short)f[2]) + b2f((unsigned short)f[3]);
            float p2 = b2f((unsigned short)f[4]) + b2f((unsigned short)f[5]);
            float p3 = b2f((unsigned short)f[6]) + b2f((unsigned short)f[7]);
            sum += (p0 + p1) + (p2 + p3);
        } else {
            #pragma unroll
            for (int j = 0; j < 8; j++) {
                int b = batch_s[i0 + j];
                if (b != cur) {
                    atomicAdd(&xg[(size_t)cur * D + tid], sum);
                    sum = 0.f; cur = b;
                }
                sum += b2f((unsigned short)f[j]);
            }
        }
    }
    atomicAdd(&xg[(size_t)cur * D + tid], sum);
}

// ---------------- K3 (MFMA, fused cat conversion) --------------------------
__global__ __launch_bounds__(256) void out_mfma_kernel(
    const float* __restrict__ xg, const float* __restrict__ xg_old,
    const unsigned short* __restrict__ Wtb, const float* __restrict__ bt,
    float* __restrict__ out, int B) {
    const int tid = threadIdx.x;
    const int w = tid >> 6, lane = tid & 63, mrow = lane & 15, q = lane >> 4;
    const int r0 = blockIdx.x * 64;

    f32x4 acc[4][4];
    #pragma unroll
    for (int i = 0; i < 4; i++)
        #pragma unroll
        for (int j = 0; j < 4; j++) acc[i][j] = (f32x4){0.f, 0.f, 0.f, 0.f};

    size_t rowbase[4];
    #pragma unroll
    for (int rb = 0; rb < 4; rb++) {
        int r = r0 + rb * 16 + mrow;
        if (r > B - 1) r = B - 1;
        rowbase[rb] = (size_t)r * D + q * 8;
    }

    #pragma unroll
    for (int ks = 0; ks < 16; ks++) {
        v8s a[4], bfr[4];
        #pragma unroll
        for (int rb = 0; rb < 4; rb++) {
            const float* src = (ks < 8) ? (xg + rowbase[rb] + ks * 32)
                                        : (xg_old + rowbase[rb] + (ks - 8) * 32);
            float4 f0 = *(const float4*)src;
            float4 f1 = *(const float4*)(src + 4);
            v8s v;
            v[0] = (short)f2b(f0.x); v[1] = (short)f2b(f0.y);
            v[2] = (short)f2b(f0.z); v[3] = (short)f2b(f0.w);
            v[4] = (short)f2b(f1.x); v[5] = (short)f2b(f1.y);
            v[6] = (short)f2b(f1.z); v[7] = (short)f2b(f1.w);
            a[rb] = v;
        }
        #pragma unroll
        for (int cb = 0; cb < 4; cb++)
            bfr[cb] = *(const v8s*)(Wtb + (((size_t)(w * 4 + cb) * 16 + ks) * 64 + lane) * 8);
        #pragma unroll
        for (int rb = 0; rb < 4; rb++)
            #pragma unroll
            for (int cb = 0; cb < 4; cb++)
                acc[rb][cb] = __builtin_amdgcn_mfma_f32_16x16x32_bf16(
                    a[rb], bfr[cb], acc[rb][cb], 0, 0, 0);
    }

    #pragma unroll
    for (int cb = 0; cb < 4; cb++) {
        int col = w * 64 + cb * 16 + mrow;
        float bias = bt[col];
        #pragma unroll
        for (int rb = 0; rb < 4; rb++) {
            #pragma unroll
            for (int reg = 0; reg < 4; reg++) {
                int row = r0 + rb * 16 + q * 4 + reg;
                if (row < B) {
                    float y = acc[rb][cb][reg] + bias;
                    y = (y >= 0.f) ? y : 0.01f * y;
                    out[(size_t)row * D + col] = y + xg_old[(size_t)row * D + col];
                }
            }
        }
    }
}

// ---------------------------------------------------------------------------
extern "C" void kernel_launch(void* const* d_in, const int* in_sizes, int n_in,
                              void* d_out, int out_size, void* d_ws, size_t ws_size,
                              hipStream_t stream) {
    const float* xg_old = (const float*)d_in[0];   // [B, D]
    const float* x      = (const float*)d_in[1];   // [N, D]
    const int*   batch  = (const int*)d_in[2];     // [N], sorted
    const float* W_gate = (const float*)d_in[3];   // [D]
    const float* b_gate = (const float*)d_in[4];   // [1]
    const float* W_feat = (const float*)d_in[5];   // [D, D]
    const float* b_feat = (const float*)d_in[6];   // [D]
    const float* W_t    = (const float*)d_in[7];   // [2D, D]
    const float* b_t    = (const float*)d_in[8];   // [D]
    float* out = (float*)d_out;                    // [B, D]

    const int N = in_sizes[1] / D;                 // 500000
    const int B = in_sizes[0] / D;                 // 10000
    const int nblk = (N + 63) / 64;                // 7813

    // workspace layout
    char* ws = (char*)d_ws;
    int*            seg_start = (int*)ws;                         // 40 KB
    float*          gate      = (float*)(ws + 0x10000);           // 2 MB
    float*          mvec      = (float*)(ws + 0x220000);          // 40 KB
    float*          invs      = (float*)(ws + 0x230000);          // 40 KB
    unsigned short* Wb32      = (unsigned short*)(ws + 0x240000); // 128 KB
    unsigned short* Wtb       = (unsigned short*)(ws + 0x260000); // 256 KB
    float*          xg        = (float*)(ws + 0x2A0000);          // 10.24 MB
    unsigned short* featbuf   = (unsigned short*)(ws + 0xCA0000); // ~275 MB

    const size_t need_full = 0xCA0000 + (size_t)nblk * (256 * FT_STRIDE * 2);
    const bool full = ws_size >= need_full;

    prep_kernel<<<3308, 256, 0, stream>>>(batch, seg_start, W_feat, Wb32, W_t, Wtb, xg, N, B);

    if (full) {
        featgate_kernel<<<nblk, 256, 0, stream>>>(
            x, Wb32, W_gate, b_gate, b_feat, gate, featbuf, N);
        stats_kernel<<<(B + 3) / 4, 256, 0, stream>>>(gate, seg_start, mvec, invs, B);
        wsum_kernel<<<nblk, 256, 0, stream>>>(featbuf, gate, batch, mvec, invs, xg, N);
    } else {
        gate_conv_kernel<false><<<2048, 256, 0, stream>>>(x, W_gate, b_gate, gate, nullptr, N);
        stats_kernel<<<(B + 3) / 4, 256, 0, stream>>>(gate, seg_start, mvec, invs, B);
        feat_attn_kernel<false><<<nblk, 256, 0, stream>>>(
            x, nullptr, Wb32, b_feat, gate, batch, mvec, invs, xg, N);
    }

    out_mfma_kernel<<<(B + 63) / 64, 256, 0, stream>>>(xg, xg_old, Wtb, b_t, out, B);
}

// Round 4
// 1004.509 us; speedup vs baseline: 1.2089x; 1.0236x over previous
//
#include <hip/hip_runtime.h>
#include <hip/hip_bf16.h>
#include <math.h>

#define D 256
#define FT_STRIDE 72   // shorts; 144 B rows, 16B-aligned; b128 walk reads hit the 8-clk floor

typedef short v8s __attribute__((ext_vector_type(8)));
typedef float f32x4 __attribute__((ext_vector_type(4)));
typedef float f32x16 __attribute__((ext_vector_type(16)));

__device__ __forceinline__ unsigned short f2b(float f) {
    return __bfloat16_as_ushort(__float2bfloat16(f));
}
__device__ __forceinline__ float b2f(unsigned short u) {
    return __bfloat162float(__ushort_as_bfloat16(u));
}
__device__ __forceinline__ float dot4(float4 a, float4 b) {
    return a.x * b.x + a.y * b.y + a.z * b.z + a.w * b.w;
}

// async global->LDS, 16 B per lane (guide m97 pattern)
__device__ __forceinline__ void gload16(const void* g, void* l) {
    __builtin_amdgcn_global_load_lds(
        (const __attribute__((address_space(1))) void*)g,
        (__attribute__((address_space(3))) void*)l, 16, 0, 0);
}

// ---------------- prep: segstart + wconv(Wf,32x32) + wconv(Wt,16x16) + zero xg
__global__ void prep_kernel(const int* __restrict__ batch, int* __restrict__ seg_start,
                            const float* __restrict__ Wf, unsigned short* __restrict__ Wb32,
                            const float* __restrict__ Wt, unsigned short* __restrict__ Wtb,
                            float* __restrict__ xg, int N, int B) {
    const int blk = blockIdx.x, tid = threadIdx.x;
    if (blk < 40) {
        int b = blk * 256 + tid;
        if (b > B) return;
        int lo = 0, hi = N;
        while (lo < hi) {
            int mid = (lo + hi) >> 1;
            if (batch[mid] < b) lo = mid + 1; else hi = mid;
        }
        seg_start[b] = lo;
    } else if (blk < 296) {
        // W_feat -> 32x32x16 B-frag order: B[k][n]: lane=((k>>3)&1)*32+(n&31), j=k&7
        int idx = (blk - 40) * 256 + tid;         // 65536
        int k = idx >> 8, n = idx & 255;
        int lane = ((k >> 3) & 1) * 32 + (n & 31);
        int j = k & 7, kst = k >> 4, ntile = n >> 5;
        Wb32[(((ntile * 16 + kst) * 64) + lane) * 8 + j] = f2b(Wf[k * 256 + n]);
    } else if (blk < 808) {
        // W_t -> 16x16x32 B-frag order (K=512): lane=((k>>3)&3)*16+(n&15), j=k&7
        int idx = (blk - 296) * 256 + tid;        // 131072
        int k = idx >> 8, n = idx & 255;
        int ntile = n >> 4, kst = k >> 5;
        int lane = ((k >> 3) & 3) * 16 + (n & 15);
        int j = k & 7;
        Wtb[(((ntile * 16 + kst) * 64) + lane) * 8 + j] = f2b(Wt[k * 256 + n]);
    } else {
        int idx = (blk - 808) * 256 + tid;        // 640000 float4 = 10.24 MB
        if (idx < 640000) ((float4*)xg)[idx] = make_float4(0.f, 0.f, 0.f, 0.f);
    }
}

// ---------------- K1 (fallback only): gate = x.Wg + bg --------------------
template<bool CONV>
__global__ __launch_bounds__(256) void gate_conv_kernel(
    const float* __restrict__ x, const float* __restrict__ Wg,
    const float* __restrict__ bg, float* __restrict__ gate,
    unsigned short* __restrict__ xb16, int N) {
    const int lane = threadIdx.x & 63;
    const int wid = blockIdx.x * 4 + (threadIdx.x >> 6);
    const int nw = gridDim.x * 4;
    const float4 wv = *(const float4*)(Wg + lane * 4);
    const float bgv = bg[0];
    for (int n = wid * 2; n < N; n += nw * 2) {
        const float4 xv0 = *(const float4*)(x + (size_t)n * D + lane * 4);
        const float4 xv1 = *(const float4*)(x + (size_t)(n + 1) * D + lane * 4);
        if (CONV) {
            ushort4 h0 = { f2b(xv0.x), f2b(xv0.y), f2b(xv0.z), f2b(xv0.w) };
            ushort4 h1 = { f2b(xv1.x), f2b(xv1.y), f2b(xv1.z), f2b(xv1.w) };
            *(ushort4*)(xb16 + (size_t)n * D + lane * 4) = h0;
            *(ushort4*)(xb16 + (size_t)(n + 1) * D + lane * 4) = h1;
        }
        float d0 = xv0.x * wv.x + xv0.y * wv.y + xv0.z * wv.z + xv0.w * wv.w;
        float d1 = xv1.x * wv.x + xv1.y * wv.y + xv1.z * wv.z + xv1.w * wv.w;
        #pragma unroll
        for (int off = 32; off; off >>= 1) {
            d0 += __shfl_xor(d0, off, 64);
            d1 += __shfl_xor(d1, off, 64);
        }
        if (lane == 0) { gate[n] = d0 + bgv; gate[n + 1] = d1 + bgv; }
    }
}

// ---------------- K1b: per-graph softmax stats (max, 1/sum) ----------------
__global__ __launch_bounds__(256) void stats_kernel(const float* __restrict__ gate,
                                                    const int* __restrict__ seg_start,
                                                    float* __restrict__ mvec,
                                                    float* __restrict__ invs, int B) {
    int wid = blockIdx.x * 4 + (threadIdx.x >> 6);
    int lane = threadIdx.x & 63;
    if (wid >= B) return;
    int s0 = seg_start[wid], s1 = seg_start[wid + 1];
    float m = -INFINITY;
    for (int i = s0 + lane; i < s1; i += 64) m = fmaxf(m, gate[i]);
    #pragma unroll
    for (int off = 32; off > 0; off >>= 1) m = fmaxf(m, __shfl_xor(m, off, 64));
    float s = 0.f;
    for (int i = s0 + lane; i < s1; i += 64) s += __expf(gate[i] - m);
    #pragma unroll
    for (int off = 32; off > 0; off >>= 1) s += __shfl_xor(s, off, 64);
    if (lane == 0) { mvec[wid] = m; invs[wid] = (s > 0.f) ? 1.f / s : 0.f; }
}

// ---------------- pass 1: fused gate + feat GEMM, feat image to global -----
// Raw-float4 rotating prefetch (4 slots, distance 3): loads are issued 3
// K-steps before the f2b conversion + gate FMAs consume them, so the
// HBM wait lands after ~3 iterations of MFMA/VALU work, not immediately.
// (Round-2 version converted at load time -> effective prefetch depth 0,
// measured 6 KB/CU in flight = latency-bound at 22% BW.)
// Steady state: 2 blocks/CU x 3 outstanding 4 KB A-chunks = 24 KB/CU in
// flight ~= the 22 KB Little's-law target for the per-CU HBM share.
__global__ __launch_bounds__(256, 2) void featgate_kernel(
    const float* __restrict__ x, const unsigned short* __restrict__ Wb32,
    const float* __restrict__ Wg, const float* __restrict__ bg,
    const float* __restrict__ bfeat, float* __restrict__ gate,
    unsigned short* __restrict__ featbuf, int N) {

    __shared__ unsigned short feat_s[256 * FT_STRIDE] __attribute__((aligned(16)));

    const int tid = threadIdx.x;
    const int n0 = blockIdx.x * 64;
    const int w = tid >> 6, lane = tid & 63;
    const int l31 = lane & 31, lh = lane >> 5;

    f32x16 acc[2][2];
    #pragma unroll
    for (int i = 0; i < 2; i++)
        #pragma unroll
        for (int j = 0; j < 2; j++)
            #pragma unroll
            for (int e = 0; e < 16; e++) acc[i][j][e] = 0.f;

    unsigned abase[2];               // element index, < 1.28e8, fits u32
    #pragma unroll
    for (int rt = 0; rt < 2; rt++) {
        int r = n0 + rt * 32 + l31;
        if (r > N - 1) r = N - 1;
        abase[rt] = (unsigned)r * D + lh * 8;
    }

    float gd0 = 0.f, gd1 = 0.f;      // fp32 gate partials (wave 0 only)
    float4 F[4][2][2];               // raw fp32 slots [slot][rt][half]
    float4 G[2][2];                  // Wg slices      [slot][half] (wave 0)
    v8s Bf[3][2];                    // B frags        [slot][ct]

    // raw loads only -- NO dependent ops at issue time
    #define LOADF(s, k)                                                      \
    {                                                                        \
        _Pragma("unroll")                                                    \
        for (int rt = 0; rt < 2; rt++) {                                     \
            const float* src = x + abase[rt] + (k) * 16;                     \
            F[s][rt][0] = *(const float4*)src;                               \
            F[s][rt][1] = *(const float4*)(src + 4);                         \
        }                                                                    \
    }
    #define LOADB(s, k)                                                      \
    {                                                                        \
        _Pragma("unroll")                                                    \
        for (int ct = 0; ct < 2; ct++)                                       \
            Bf[s][ct] = *(const v8s*)(Wb32 +                                 \
                (((size_t)(w * 2 + ct) * 16 + (k)) * 64 + lane) * 8);        \
    }
    #define LOADG(s, k)                                                      \
    {                                                                        \
        G[s][0] = *(const float4*)(Wg + lh * 8 + (k) * 16);                  \
        G[s][1] = *(const float4*)(Wg + lh * 8 + (k) * 16 + 4);              \
    }

    // prologue: A depth 3, B depth 2, G depth 1
    LOADF(0, 0) LOADF(1, 1) LOADF(2, 2)
    LOADB(0, 0) LOADB(1, 1)
    if (w == 0) LOADG(0, 0)

    #pragma unroll
    for (int ks = 0; ks < 16; ks++) {
        const int cs = ks & 3, cb = ks % 3, gs = ks & 1;
        // issue next loads first (independent of this step's consumes)
        if (ks < 13) LOADF((ks + 3) & 3, ks + 3)
        if (ks < 14) LOADB((ks + 2) % 3, ks + 2)
        if (w == 0 && ks < 15) LOADG((ks + 1) & 1, ks + 1)

        // consume slot cs: gate FMAs + f2b conversion (waits on 3-step-old loads)
        if (w == 0) {
            gd0 += dot4(F[cs][0][0], G[gs][0]) + dot4(F[cs][0][1], G[gs][1]);
            gd1 += dot4(F[cs][1][0], G[gs][0]) + dot4(F[cs][1][1], G[gs][1]);
        }
        v8s a0, a1;
        {
            float4 f0 = F[cs][0][0], f1 = F[cs][0][1];
            a0[0] = (short)f2b(f0.x); a0[1] = (short)f2b(f0.y);
            a0[2] = (short)f2b(f0.z); a0[3] = (short)f2b(f0.w);
            a0[4] = (short)f2b(f1.x); a0[5] = (short)f2b(f1.y);
            a0[6] = (short)f2b(f1.z); a0[7] = (short)f2b(f1.w);
            float4 f2 = F[cs][1][0], f3 = F[cs][1][1];
            a1[0] = (short)f2b(f2.x); a1[1] = (short)f2b(f2.y);
            a1[2] = (short)f2b(f2.z); a1[3] = (short)f2b(f2.w);
            a1[4] = (short)f2b(f3.x); a1[5] = (short)f2b(f3.y);
            a1[6] = (short)f2b(f3.z); a1[7] = (short)f2b(f3.w);
        }
        #pragma unroll
        for (int ct = 0; ct < 2; ct++) {
            acc[0][ct] = __builtin_amdgcn_mfma_f32_32x32x16_bf16(
                a0, Bf[cb][ct], acc[0][ct], 0, 0, 0);
            acc[1][ct] = __builtin_amdgcn_mfma_f32_32x32x16_bf16(
                a1, Bf[cb][ct], acc[1][ct], 0, 0, 0);
        }
    }
    #undef LOADF
    #undef LOADB
    #undef LOADG

    // gate finalize: row r = abase>>8 (lh==0); clamped tail rows write same value
    if (w == 0) {
        const float bgv = bg[0];
        #pragma unroll
        for (int rt = 0; rt < 2; rt++) {
            float d = (rt == 0) ? gd0 : gd1;
            d += __shfl_xor(d, 32, 64);
            if (lh == 0) gate[abase[rt] >> 8] = d + bgv;
        }
    }

    // epilogue: bias + leaky -> bf16 transposed LDS (NO alpha here; pass 3 applies it)
    // C/D 32x32: col=lane&31, row=(reg&3)+8*(reg>>2)+4*(lane>>5)
    #pragma unroll
    for (int ct = 0; ct < 2; ct++) {
        int col = w * 64 + ct * 32 + l31;
        float bias = bfeat[col];
        #pragma unroll
        for (int rt = 0; rt < 2; rt++) {
            #pragma unroll
            for (int g = 0; g < 4; g++) {
                int rbase = rt * 32 + g * 8 + 4 * lh;
                ushort4 h;
                #pragma unroll
                for (int rr = 0; rr < 4; rr++) {
                    float y = acc[rt][ct][g * 4 + rr] + bias;
                    y = (y >= 0.f) ? y : 0.01f * y;
                    ((unsigned short*)&h)[rr] = f2b(y);
                }
                *(ushort4*)(&feat_s[col * FT_STRIDE + rbase]) = h;
            }
        }
    }
    __syncthreads();

    // linear image copy LDS->global, coalesced 16 B/lane (pad rows included)
    unsigned short* dst = featbuf + (size_t)blockIdx.x * (256 * FT_STRIDE);
    #pragma unroll
    for (int it = 0; it < 9; it++) {
        int off = it * 2048 + tid * 8;           // shorts
        *(v8s*)(dst + off) = *(const v8s*)(feat_s + off);
    }
}

// ---------------- pass 3: stage image via global_load_lds + alpha walk -----
__global__ __launch_bounds__(256, 4) void wsum_kernel(
    const unsigned short* __restrict__ featbuf, const float* __restrict__ gate,
    const int* __restrict__ batch, const float* __restrict__ mvec,
    const float* __restrict__ invs, float* __restrict__ xg, int N) {

    __shared__ unsigned short feat_s[256 * FT_STRIDE] __attribute__((aligned(16)));
    __shared__ float alpha_s[64];
    __shared__ int batch_s[64];

    const int tid = threadIdx.x;
    const int n0 = blockIdx.x * 64;

    const unsigned short* src = featbuf + (size_t)blockIdx.x * (256 * FT_STRIDE);
    #pragma unroll
    for (int it = 0; it < 9; it++) {
        int off = it * 2048 + tid * 8;           // shorts; 16 B per lane, linear
        gload16(src + off, feat_s + off);
    }

    if (tid < 64) {
        int n = n0 + tid;
        if (n < N) {
            int b = batch[n];
            batch_s[tid] = b;
            alpha_s[tid] = __expf(gate[n] - mvec[b]) * invs[b];
        } else {            // pad with last valid segment, zero weight
            batch_s[tid] = batch[N - 1];
            alpha_s[tid] = 0.f;
        }
    }
    __syncthreads();        // waits vmcnt(0) for global_load_lds + alpha_s/batch_s

    // walk: thread tid owns col tid; alpha applied here (broadcast LDS reads)
    float sum = 0.f;
    int cur = batch_s[0];
    #pragma unroll
    for (int i0 = 0; i0 < 64; i0 += 8) {
        v8s f = *(const v8s*)(&feat_s[tid * FT_STRIDE + i0]);
        int b0 = batch_s[i0], b7 = batch_s[i0 + 7];
        if (b0 == b7) {                 // no boundary in group (common)
            if (b0 != cur) {
                atomicAdd(&xg[(size_t)cur * D + tid], sum);
                sum = 0.f; cur = b0;
            }
            float s0 = alpha_s[i0 + 0] * b2f((unsigned short)f[0])
                     + alpha_s[i0 + 1] * b2f((unsigned short)f[1]);
            float s1 = alpha_s[i0 + 2] * b2f((unsigned short)f[2])
                     + alpha_s[i0 + 3] * b2f((unsigned short)f[3]);
            float s2 = alpha_s[i0 + 4] * b2f((unsigned short)f[4])
                     + alpha_s[i0 + 5] * b2f((unsigned short)f[5]);
            float s3 = alpha_s[i0 + 6] * b2f((unsigned short)f[6])
                     + alpha_s[i0 + 7] * b2f((unsigned short)f[7]);
            sum += (s0 + s1) + (s2 + s3);
        } else {
            #pragma unroll
            for (int j = 0; j < 8; j++) {
                int b = batch_s[i0 + j];
                if (b != cur) {
                    atomicAdd(&xg[(size_t)cur * D + tid], sum);
                    sum = 0.f; cur = b;
                }
                sum = fmaf(alpha_s[i0 + j], b2f((unsigned short)f[j]), sum);
            }
        }
    }
    atomicAdd(&xg[(size_t)cur * D + tid], sum);
}

// ---------------- fallback pass 2 (ws too small): fp32-in feat GEMM + walk -
template<bool BF16IN>
__global__ __launch_bounds__(256, 4) void feat_attn_kernel(
    const float* __restrict__ x, const unsigned short* __restrict__ xb16,
    const unsigned short* __restrict__ Wb32,
    const float* __restrict__ bfeat, const float* __restrict__ gate,
    const int* __restrict__ batch, const float* __restrict__ mvec,
    const float* __restrict__ invs, float* __restrict__ xg, int N) {

    __shared__ unsigned short feat_s[256 * FT_STRIDE] __attribute__((aligned(16)));
    __shared__ float alpha_s[64];
    __shared__ int batch_s[64];

    const int tid = threadIdx.x;
    const int n0 = blockIdx.x * 64;

    if (tid < 64) {
        int n = n0 + tid;
        if (n < N) {
            int b = batch[n];
            batch_s[tid] = b;
            alpha_s[tid] = __expf(gate[n] - mvec[b]) * invs[b];
        } else {
            batch_s[tid] = batch[N - 1];
            alpha_s[tid] = 0.f;
        }
    }

    const int w = tid >> 6, lane = tid & 63;
    const int l31 = lane & 31, lh = lane >> 5;

    f32x16 acc[2][2];
    #pragma unroll
    for (int i = 0; i < 2; i++)
        #pragma unroll
        for (int j = 0; j < 2; j++)
            #pragma unroll
            for (int e = 0; e < 16; e++) acc[i][j][e] = 0.f;

    size_t abase[2];
    #pragma unroll
    for (int rt = 0; rt < 2; rt++) {
        int r = n0 + rt * 32 + l31;
        if (r > N - 1) r = N - 1;
        abase[rt] = (size_t)r * D + lh * 8;
    }

    v8s A[3][2], Bf[2][2];
    #pragma unroll
    for (int p = 0; p < 2; p++) {
        #pragma unroll
        for (int rt = 0; rt < 2; rt++) {
            if (BF16IN) A[p][rt] = *(const v8s*)(xb16 + abase[rt] + p * 16);
            else {
                const float* src = x + abase[rt] + p * 16;
                float4 f0 = *(const float4*)src, f1 = *(const float4*)(src + 4);
                v8s v; v[0]=(short)f2b(f0.x); v[1]=(short)f2b(f0.y);
                v[2]=(short)f2b(f0.z); v[3]=(short)f2b(f0.w);
                v[4]=(short)f2b(f1.x); v[5]=(short)f2b(f1.y);
                v[6]=(short)f2b(f1.z); v[7]=(short)f2b(f1.w);
                A[p][rt] = v;
            }
        }
        #pragma unroll
        for (int ct = 0; ct < 2; ct++)
            Bf[p][ct] = *(const v8s*)(Wb32 + (((size_t)(w * 2 + ct) * 16 + p) * 64 + lane) * 8);
    }

    #pragma unroll
    for (int ks = 0; ks < 16; ks++) {
        const int cs = ks % 3, bs = ks & 1;
        if (ks < 14) {
            const int ns = (ks + 2) % 3;
            #pragma unroll
            for (int rt = 0; rt < 2; rt++) {
                if (BF16IN) A[ns][rt] = *(const v8s*)(xb16 + abase[rt] + (ks + 2) * 16);
                else {
                    const float* src = x + abase[rt] + (ks + 2) * 16;
                    float4 f0 = *(const float4*)src, f1 = *(const float4*)(src + 4);
                    v8s v; v[0]=(short)f2b(f0.x); v[1]=(short)f2b(f0.y);
                    v[2]=(short)f2b(f0.z); v[3]=(short)f2b(f0.w);
                    v[4]=(short)f2b(f1.x); v[5]=(short)f2b(f1.y);
                    v[6]=(short)f2b(f1.z); v[7]=(short)f2b(f1.w);
                    A[ns][rt] = v;
                }
            }
        }
        if (ks < 15) {
            const int nb = (ks + 1) & 1;
            #pragma unroll
            for (int ct = 0; ct < 2; ct++)
                Bf[nb][ct] = *(const v8s*)(Wb32 + (((size_t)(w * 2 + ct) * 16 + ks + 1) * 64 + lane) * 8);
        }
        #pragma unroll
        for (int rt = 0; rt < 2; rt++)
            #pragma unroll
            for (int ct = 0; ct < 2; ct++)
                acc[rt][ct] = __builtin_amdgcn_mfma_f32_32x32x16_bf16(
                    A[cs][rt], Bf[bs][ct], acc[rt][ct], 0, 0, 0);
    }

    __syncthreads();

    #pragma unroll
    for (int ct = 0; ct < 2; ct++) {
        int col = w * 64 + ct * 32 + l31;
        float bias = bfeat[col];
        #pragma unroll
        for (int rt = 0; rt < 2; rt++) {
            #pragma unroll
            for (int g = 0; g < 4; g++) {
                int rbase = rt * 32 + g * 8 + 4 * lh;
                ushort4 h;
                #pragma unroll
                for (int rr = 0; rr < 4; rr++) {
                    float y = acc[rt][ct][g * 4 + rr] + bias;
                    y = (y >= 0.f) ? y : 0.01f * y;
                    y *= alpha_s[rbase + rr];
                    ((unsigned short*)&h)[rr] = f2b(y);
                }
                *(ushort4*)(&feat_s[col * FT_STRIDE + rbase]) = h;
            }
        }
    }
    __syncthreads();

    float sum = 0.f;
    int cur = batch_s[0];
    #pragma unroll
    for (int i0 = 0; i0 < 64; i0 += 8) {
        v8s f = *(const v8s*)(&feat_s[tid * FT_STRIDE + i0]);
        int b0 = batch_s[i0], b7 = batch_s[i0 + 7];
        if (b0 == b7) {
            if (b0 != cur) {
                atomicAdd(&xg[(size_t)cur * D + tid], sum);
                sum = 0.f; cur = b0;
            }
            float p0 = b2f((unsigned short)f[0]) + b2f((unsigned short)f[1]);
            float p1 = b2f((unsigned short)f[2]) + b2f((unsigned short)f[3]);
            float p2 = b2f((unsigned short)f[4]) + b2f((unsigned short)f[5]);
            float p3 = b2f((unsigned short)f[6]) + b2f((unsigned short)f[7]);
            sum += (p0 + p1) + (p2 + p3);
        } else {
            #pragma unroll
            for (int j = 0; j < 8; j++) {
                int b = batch_s[i0 + j];
                if (b != cur) {
                    atomicAdd(&xg[(size_t)cur * D + tid], sum);
                    sum = 0.f; cur = b;
                }
                sum += b2f((unsigned short)f[j]);
            }
        }
    }
    atomicAdd(&xg[(size_t)cur * D + tid], sum);
}

// ---------------- K3 (MFMA, fused cat conversion) --------------------------
__global__ __launch_bounds__(256) void out_mfma_kernel(
    const float* __restrict__ xg, const float* __restrict__ xg_old,
    const unsigned short* __restrict__ Wtb, const float* __restrict__ bt,
    float* __restrict__ out, int B) {
    const int tid = threadIdx.x;
    const int w = tid >> 6, lane = tid & 63, mrow = lane & 15, q = lane >> 4;
    const int r0 = blockIdx.x * 64;

    f32x4 acc[4][4];
    #pragma unroll
    for (int i = 0; i < 4; i++)
        #pragma unroll
        for (int j = 0; j < 4; j++) acc[i][j] = (f32x4){0.f, 0.f, 0.f, 0.f};

    size_t rowbase[4];
    #pragma unroll
    for (int rb = 0; rb < 4; rb++) {
        int r = r0 + rb * 16 + mrow;
        if (r > B - 1) r = B - 1;
        rowbase[rb] = (size_t)r * D + q * 8;
    }

    #pragma unroll
    for (int ks = 0; ks < 16; ks++) {
        v8s a[4], bfr[4];
        #pragma unroll
        for (int rb = 0; rb < 4; rb++) {
            const float* src = (ks < 8) ? (xg + rowbase[rb] + ks * 32)
                                        : (xg_old + rowbase[rb] + (ks - 8) * 32);
            float4 f0 = *(const float4*)src;
            float4 f1 = *(const float4*)(src + 4);
            v8s v;
            v[0] = (short)f2b(f0.x); v[1] = (short)f2b(f0.y);
            v[2] = (short)f2b(f0.z); v[3] = (short)f2b(f0.w);
            v[4] = (short)f2b(f1.x); v[5] = (short)f2b(f1.y);
            v[6] = (short)f2b(f1.z); v[7] = (short)f2b(f1.w);
            a[rb] = v;
        }
        #pragma unroll
        for (int cb = 0; cb < 4; cb++)
            bfr[cb] = *(const v8s*)(Wtb + (((size_t)(w * 4 + cb) * 16 + ks) * 64 + lane) * 8);
        #pragma unroll
        for (int rb = 0; rb < 4; rb++)
            #pragma unroll
            for (int cb = 0; cb < 4; cb++)
                acc[rb][cb] = __builtin_amdgcn_mfma_f32_16x16x32_bf16(
                    a[rb], bfr[cb], acc[rb][cb], 0, 0, 0);
    }

    #pragma unroll
    for (int cb = 0; cb < 4; cb++) {
        int col = w * 64 + cb * 16 + mrow;
        float bias = bt[col];
        #pragma unroll
        for (int rb = 0; rb < 4; rb++) {
            #pragma unroll
            for (int reg = 0; reg < 4; reg++) {
                int row = r0 + rb * 16 + q * 4 + reg;
                if (row < B) {
                    float y = acc[rb][cb][reg] + bias;
                    y = (y >= 0.f) ? y : 0.01f * y;
                    out[(size_t)row * D + col] = y + xg_old[(size_t)row * D + col];
                }
            }
        }
    }
}

// ---------------------------------------------------------------------------
extern "C" void kernel_launch(void* const* d_in, const int* in_sizes, int n_in,
                              void* d_out, int out_size, void* d_ws, size_t ws_size,
                              hipStream_t stream) {
    const float* xg_old = (const float*)d_in[0];   // [B, D]
    const float* x      = (const float*)d_in[1];   // [N, D]
    const int*   batch  = (const int*)d_in[2];     // [N], sorted
    const float* W_gate = (const float*)d_in[3];   // [D]
    const float* b_gate = (const float*)d_in[4];   // [1]
    const float* W_feat = (const float*)d_in[5];   // [D, D]
    const float* b_feat = (const float*)d_in[6];   // [D]
    const float* W_t    = (const float*)d_in[7];   // [2D, D]
    const float* b_t    = (const float*)d_in[8];   // [D]
    float* out = (float*)d_out;                    // [B, D]

    const int N = in_sizes[1] / D;                 // 500000
    const int B = in_sizes[0] / D;                 // 10000
    const int nblk = (N + 63) / 64;                // 7813

    // workspace layout
    char* ws = (char*)d_ws;
    int*            seg_start = (int*)ws;                         // 40 KB
    float*          gate      = (float*)(ws + 0x10000);           // 2 MB
    float*          mvec      = (float*)(ws + 0x220000);          // 40 KB
    float*          invs      = (float*)(ws + 0x230000);          // 40 KB
    unsigned short* Wb32      = (unsigned short*)(ws + 0x240000); // 128 KB
    unsigned short* Wtb       = (unsigned short*)(ws + 0x260000); // 256 KB
    float*          xg        = (float*)(ws + 0x2A0000);          // 10.24 MB
    unsigned short* featbuf   = (unsigned short*)(ws + 0xCA0000); // ~275 MB

    const size_t need_full = 0xCA0000 + (size_t)nblk * (256 * FT_STRIDE * 2);
    const bool full = ws_size >= need_full;

    prep_kernel<<<3308, 256, 0, stream>>>(batch, seg_start, W_feat, Wb32, W_t, Wtb, xg, N, B);

    if (full) {
        featgate_kernel<<<nblk, 256, 0, stream>>>(
            x, Wb32, W_gate, b_gate, b_feat, gate, featbuf, N);
        stats_kernel<<<(B + 3) / 4, 256, 0, stream>>>(gate, seg_start, mvec, invs, B);
        wsum_kernel<<<nblk, 256, 0, stream>>>(featbuf, gate, batch, mvec, invs, xg, N);
    } else {
        gate_conv_kernel<false><<<2048, 256, 0, stream>>>(x, W_gate, b_gate, gate, nullptr, N);
        stats_kernel<<<(B + 3) / 4, 256, 0, stream>>>(gate, seg_start, mvec, invs, B);
        feat_attn_kernel<false><<<nblk, 256, 0, stream>>>(
            x, nullptr, Wb32, b_feat, gate, batch, mvec, invs, xg, N);
    }

    out_mfma_kernel<<<(B + 63) / 64, 256, 0, stream>>>(xg, xg_old, Wtb, b_t, out, B);
}